// Round 1
// baseline (202.549 us; speedup 1.0000x reference)
//
#include <hip/hip_runtime.h>
#include <hip/hip_bf16.h>

#define B_    32
#define H_    512
#define W_    512
#define KEEP_ 64
#define FD_   256
#define FANIN 4096

typedef __attribute__((ext_vector_type(8))) _Float16 half8;
typedef __attribute__((ext_vector_type(4))) float    f32x4;

// ---------------- K0: precompute f16 basis tables + fc_w*16 in f16 ----------
__global__ __launch_bounds__(256) void k_prep(const float* __restrict__ fc_w,
                                              _Float16* __restrict__ basisA,   // [128][512]  rows 0..63 cos, 64..127 sin
                                              _Float16* __restrict__ basisW,   // [64][1024]  j<512 cos/16, j>=512 -sin/16
                                              _Float16* __restrict__ fcwb)     // [256][4096] fc_w * 16
{
    int gid    = blockIdx.x * blockDim.x + threadIdx.x;
    int stride = gridDim.x * blockDim.x;
    const float STEP = 6.28318530717958647692f / 512.0f;

    for (int i = gid; i < 128 * 512; i += stride) {
        int r = i >> 9, h = i & 511;
        int ph = ((r & 63) * h) & 511;
        float ang = (float)ph * STEP;
        float v = (r < 64) ? cosf(ang) : sinf(ang);
        basisA[i] = (_Float16)v;
    }
    for (int i = gid; i < 64 * 1024; i += stride) {
        int n = i >> 10, j = i & 1023;
        int ph = (n * (j & 511)) & 511;
        float ang = (float)ph * STEP;
        float v = (j < 512) ? cosf(ang) : -sinf(ang);
        basisW[i] = (_Float16)(v * 0.0625f);      // fold 1/16 scale
    }
    for (int i = gid; i < 256 * 4096; i += stride)
        fcwb[i] = (_Float16)(fc_w[i] * 16.0f);    // compensate 1/16 scale
}

// ---------------- K1: grayscale + transpose -> grayT[b][w][h] f16 -----------
__global__ __launch_bounds__(256) void k_gray(const float* __restrict__ x,
                                              _Float16* __restrict__ grayT)
{
    int b  = blockIdx.z;
    int h0 = blockIdx.y * 64;
    int w0 = blockIdx.x * 64;
    __shared__ float tile[64][65];

    const float* xb = x + (size_t)b * 3 * H_ * W_;
    int t = threadIdx.x;

    // load 64x64 tile, float4 per thread (1024 float4 slots / 256 threads = 4)
    for (int i = 0; i < 4; ++i) {
        int slot = t + i * 256;
        int hh = slot >> 4;          // 0..63
        int w4 = slot & 15;          // 0..15
        const float* p0 = xb + (size_t)(h0 + hh) * W_ + w0 + w4 * 4;
        const float* p1 = p0 + (size_t)H_ * W_;
        const float* p2 = p1 + (size_t)H_ * W_;
        float4 r = *(const float4*)p0;
        float4 g = *(const float4*)p1;
        float4 bl = *(const float4*)p2;
        tile[hh][w4 * 4 + 0] = 0.299f * r.x + 0.587f * g.x + 0.114f * bl.x;
        tile[hh][w4 * 4 + 1] = 0.299f * r.y + 0.587f * g.y + 0.114f * bl.y;
        tile[hh][w4 * 4 + 2] = 0.299f * r.z + 0.587f * g.z + 0.114f * bl.z;
        tile[hh][w4 * 4 + 3] = 0.299f * r.w + 0.587f * g.w + 0.114f * bl.w;
    }
    __syncthreads();

    _Float16* gb = grayT + (size_t)b * W_ * H_;
    for (int i = 0; i < 16; ++i) {
        int idx = t + i * 256;
        int ww = idx >> 6;           // 0..63
        int hh = idx & 63;           // 0..63, contiguous across lanes -> coalesced
        gb[(size_t)(w0 + ww) * H_ + h0 + hh] = (_Float16)tile[hh][ww];
    }
}

// ---------------- K2: stage-1 GEMM  T[b][kh][cs][w] = basisA x gray --------
__global__ __launch_bounds__(256) void k_stage1(const _Float16* __restrict__ basisA,
                                                const _Float16* __restrict__ grayT,
                                                _Float16* __restrict__ T)
{
    int b  = blockIdx.y;
    int n0 = blockIdx.x * 64;               // w-tile
    int lane = threadIdx.x & 63;
    int wv   = threadIdx.x >> 6;            // wave id: m rows [wv*32, wv*32+32)
    int l15  = lane & 15;
    int quad = lane >> 4;

    f32x4 acc[2][4];
    for (int i = 0; i < 2; ++i)
        for (int j = 0; j < 4; ++j)
            acc[i][j] = (f32x4){0.f, 0.f, 0.f, 0.f};

    const _Float16* gb = grayT + (size_t)b * W_ * H_;

    for (int k0 = 0; k0 < 512; k0 += 32) {
        int kc = k0 + quad * 8;
        half8 a[2], bv[4];
        for (int mi = 0; mi < 2; ++mi) {
            int row = wv * 32 + mi * 16 + l15;
            a[mi] = *(const half8*)(basisA + row * 512 + kc);
        }
        for (int ni = 0; ni < 4; ++ni) {
            int row = n0 + ni * 16 + l15;   // w index
            bv[ni] = *(const half8*)(gb + (size_t)row * 512 + kc);
        }
        for (int mi = 0; mi < 2; ++mi)
            for (int ni = 0; ni < 4; ++ni)
                acc[mi][ni] = __builtin_amdgcn_mfma_f32_16x16x32_f16(
                    a[mi], bv[ni], acc[mi][ni], 0, 0, 0);
    }

    _Float16* Tb = T + (size_t)b * 64 * 1024;
    for (int mi = 0; mi < 2; ++mi)
        for (int ni = 0; ni < 4; ++ni)
            for (int r = 0; r < 4; ++r) {
                int m = wv * 32 + mi * 16 + quad * 4 + r;   // basis row
                int n = n0 + ni * 16 + l15;                 // w
                int off = (m < 64) ? (m * 1024 + n) : ((m - 64) * 1024 + 512 + n);
                Tb[off] = (_Float16)acc[mi][ni][r];
            }
}

// ---------------- K3: stage-2 GEMM  X[b][kh][kw] (scaled 1/16) -------------
__global__ __launch_bounds__(256) void k_stage2(const _Float16* __restrict__ T,
                                                const _Float16* __restrict__ basisW,
                                                _Float16* __restrict__ X)
{
    int b    = blockIdx.x;
    int lane = threadIdx.x & 63;
    int wv   = threadIdx.x >> 6;            // m rows [wv*16, wv*16+16)
    int l15  = lane & 15;
    int quad = lane >> 4;

    f32x4 acc[4];
    for (int i = 0; i < 4; ++i) acc[i] = (f32x4){0.f, 0.f, 0.f, 0.f};

    const _Float16* Tb = T + (size_t)b * 64 * 1024;

    for (int k0 = 0; k0 < 1024; k0 += 32) {
        int kc = k0 + quad * 8;
        half8 a = *(const half8*)(Tb + (wv * 16 + l15) * 1024 + kc);
        for (int ni = 0; ni < 4; ++ni) {
            half8 bv = *(const half8*)(basisW + (ni * 16 + l15) * 1024 + kc);
            acc[ni] = __builtin_amdgcn_mfma_f32_16x16x32_f16(a, bv, acc[ni], 0, 0, 0);
        }
    }

    _Float16* Xb = X + (size_t)b * 4096;
    for (int ni = 0; ni < 4; ++ni)
        for (int r = 0; r < 4; ++r) {
            int kh = wv * 16 + quad * 4 + r;
            int kw = ni * 16 + l15;
            Xb[kh * 64 + kw] = (_Float16)acc[ni][r];
        }
}

// ---------------- K4: FC  out[32][256] = X * fcwb^T + fc_b -----------------
__global__ __launch_bounds__(64) void k_fc(const _Float16* __restrict__ X,
                                           const _Float16* __restrict__ fcwb,
                                           const float* __restrict__ fc_b,
                                           float* __restrict__ out)
{
    int nb   = blockIdx.x & 15;             // f tile of 16
    int kc   = blockIdx.x >> 4;             // k chunk of 1024
    int lane = threadIdx.x;
    int l15  = lane & 15;
    int quad = lane >> 4;

    f32x4 acc[2];
    acc[0] = (f32x4){0.f, 0.f, 0.f, 0.f};
    acc[1] = (f32x4){0.f, 0.f, 0.f, 0.f};

    int kbeg = kc * 1024;
    for (int k0 = kbeg; k0 < kbeg + 1024; k0 += 32) {
        int kk = k0 + quad * 8;
        half8 a0 = *(const half8*)(X + (size_t)(l15)      * 4096 + kk);
        half8 a1 = *(const half8*)(X + (size_t)(16 + l15) * 4096 + kk);
        half8 b0 = *(const half8*)(fcwb + (size_t)(nb * 16 + l15) * 4096 + kk);
        acc[0] = __builtin_amdgcn_mfma_f32_16x16x32_f16(a0, b0, acc[0], 0, 0, 0);
        acc[1] = __builtin_amdgcn_mfma_f32_16x16x32_f16(a1, b0, acc[1], 0, 0, 0);
    }

    for (int mi = 0; mi < 2; ++mi)
        for (int r = 0; r < 4; ++r) {
            int m = mi * 16 + quad * 4 + r;     // batch row
            int f = nb * 16 + l15;              // feature
            float v = acc[mi][r];
            if (kc == 0) v += fc_b[f];
            atomicAdd(out + m * 256 + f, v);
        }
}

// ---------------------------------------------------------------------------
extern "C" void kernel_launch(void* const* d_in, const int* in_sizes, int n_in,
                              void* d_out, int out_size, void* d_ws, size_t ws_size,
                              hipStream_t stream) {
    const float* x    = (const float*)d_in[0];
    const float* fc_w = (const float*)d_in[1];
    const float* fc_b = (const float*)d_in[2];
    float* out = (float*)d_out;

    char* ws = (char*)d_ws;
    _Float16* basisA = (_Float16*)(ws + 0);          //  128*512*2  = 131072
    _Float16* basisW = (_Float16*)(ws + 131072);     //  64*1024*2  = 131072
    _Float16* fcwb   = (_Float16*)(ws + 262144);     //  256*4096*2 = 2097152
    _Float16* grayT  = (_Float16*)(ws + 2359296);    //  32*512*512*2 = 16777216
    _Float16* T      = (_Float16*)(ws + 19136512);   //  32*64*1024*2 = 4194304
    _Float16* X      = (_Float16*)(ws + 23330816);   //  32*4096*2  = 262144
                                                     //  total 23.6 MB

    k_prep<<<512, 256, 0, stream>>>(fc_w, basisA, basisW, fcwb);
    k_gray<<<dim3(8, 8, 32), 256, 0, stream>>>(x, grayT);
    k_stage1<<<dim3(8, 32), 256, 0, stream>>>(basisA, grayT, T);
    k_stage2<<<32, 256, 0, stream>>>(T, basisW, X);
    hipMemsetAsync(d_out, 0, (size_t)out_size * sizeof(float), stream);
    k_fc<<<64, 64, 0, stream>>>(X, fcwb, fc_b, out);
}

// Round 2
// 188.814 us; speedup vs baseline: 1.0727x; 1.0727x over previous
//
#include <hip/hip_runtime.h>
#include <hip/hip_bf16.h>

#define HW_ (512 * 512)

typedef __attribute__((ext_vector_type(8))) _Float16 half8;
typedef __attribute__((ext_vector_type(4))) _Float16 half4;
typedef __attribute__((ext_vector_type(4))) float    f32x4;

// ---------------- K0: basis table [128][512], rows 0..63 cos, 64..127 sin --
__global__ __launch_bounds__(256) void k_prep(_Float16* __restrict__ basisA) {
    int i = blockIdx.x * 256 + threadIdx.x;   // grid = 256 blocks -> 65536
    if (i < 128 * 512) {
        int r = i >> 9, h = i & 511;
        int ph = ((r & 63) * h) & 511;
        float ang = (float)ph * (6.28318530717958647692f / 512.0f);
        basisA[i] = (_Float16)((r < 64) ? cosf(ang) : sinf(ang));
    }
}

// ---------------- K1: fused gray + w-FFT.  P[b][row][h], row<64: cos (Pc),
//                  row>=64: MINUS sin (-Ps), so stage-2 is a plain sum. -----
__global__ __launch_bounds__(256) void k1(const float* __restrict__ x,
                                          const _Float16* __restrict__ basisA,
                                          _Float16* __restrict__ P)
{
    __shared__ _Float16 g[32][520];          // pad 8 halfs: 2-way (free) reads
    int h0 = blockIdx.x * 32;                // 16 h-tiles
    int b  = blockIdx.y;
    int t  = threadIdx.x;
    const float* xb = x + (size_t)b * 3 * HW_;

    // stage gray slab [32 h][512 w] into LDS; fully coalesced x reads
    for (int i = 0; i < 16; ++i) {
        int slot = t + i * 256;
        int hh = slot >> 7;                  // 0..31
        int w4 = slot & 127;                 // float4 index along w
        const float* p = xb + (size_t)(h0 + hh) * 512 + w4 * 4;
        float4 r  = *(const float4*)p;
        float4 gg = *(const float4*)(p + HW_);
        float4 bb = *(const float4*)(p + 2 * HW_);
        half4 o;
        o.x = (_Float16)(0.299f * r.x + 0.587f * gg.x + 0.114f * bb.x);
        o.y = (_Float16)(0.299f * r.y + 0.587f * gg.y + 0.114f * bb.y);
        o.z = (_Float16)(0.299f * r.z + 0.587f * gg.z + 0.114f * bb.z);
        o.w = (_Float16)(0.299f * r.w + 0.587f * gg.w + 0.114f * bb.w);
        *(half4*)&g[hh][w4 * 4] = o;
    }
    __syncthreads();

    int lane = t & 63, wv = t >> 6, l15 = lane & 15, quad = lane >> 4;
    f32x4 acc[2][2];
    for (int i = 0; i < 2; ++i)
        for (int j = 0; j < 2; ++j) acc[i][j] = (f32x4){0.f, 0.f, 0.f, 0.f};

    for (int k0 = 0; k0 < 512; k0 += 32) {   // k = w
        int kc = k0 + quad * 8;
        half8 a[2], bv[2];
        for (int mi = 0; mi < 2; ++mi)
            a[mi] = *(const half8*)(basisA + (wv * 32 + mi * 16 + l15) * 512 + kc);
        for (int ni = 0; ni < 2; ++ni)
            bv[ni] = *(const half8*)&g[ni * 16 + l15][kc];
        for (int mi = 0; mi < 2; ++mi)
            for (int ni = 0; ni < 2; ++ni)
                acc[mi][ni] = __builtin_amdgcn_mfma_f32_16x16x32_f16(
                    a[mi], bv[ni], acc[mi][ni], 0, 0, 0);
    }

    _Float16* Pb = P + (size_t)b * 128 * 512;
    for (int mi = 0; mi < 2; ++mi)
        for (int ni = 0; ni < 2; ++ni)
            for (int r = 0; r < 4; ++r) {
                int m = wv * 32 + mi * 16 + quad * 4 + r;   // basis row
                int h = h0 + ni * 16 + l15;
                float v = acc[mi][ni][r];
                if (m >= 64) v = -v;                        // fold -sin
                Pb[m * 512 + h] = (_Float16)v;
            }
}

// ---------------- K2: h-FFT.  X[b][kh][kw] = sum_k A2[kh,k]*B2[kw,k], K=1024
//                  A2 = basisA rows (cos | sin), B2 = P rows (Pc | -Ps). ----
__global__ __launch_bounds__(128) void k2(const _Float16* __restrict__ basisA,
                                          const _Float16* __restrict__ P,
                                          _Float16* __restrict__ X)
{
    int b     = blockIdx.y;
    int mbase = blockIdx.x * 32 + (threadIdx.x >> 6) * 16;  // kh tile
    int lane  = threadIdx.x & 63, l15 = lane & 15, quad = lane >> 4;

    f32x4 acc[4];
    for (int i = 0; i < 4; ++i) acc[i] = (f32x4){0.f, 0.f, 0.f, 0.f};

    const _Float16* Pb = P + (size_t)b * 128 * 512;

    for (int k0 = 0; k0 < 1024; k0 += 32) {
        int kc  = k0 + quad * 8;
        int hi  = (kc >= 512) ? 64 : 0;      // uniform within a k0 step
        int col = kc & 511;
        half8 a = *(const half8*)(basisA + (hi + mbase + l15) * 512 + col);
        for (int ni = 0; ni < 4; ++ni) {
            half8 bv = *(const half8*)(Pb + (hi + ni * 16 + l15) * 512 + col);
            acc[ni] = __builtin_amdgcn_mfma_f32_16x16x32_f16(a, bv, acc[ni], 0, 0, 0);
        }
    }

    _Float16* Xb = X + (size_t)b * 4096;
    for (int ni = 0; ni < 4; ++ni)
        for (int r = 0; r < 4; ++r) {
            int kh = mbase + quad * 4 + r;
            int kw = ni * 16 + l15;
            Xb[kh * 64 + kw] = (_Float16)(acc[ni][r] * 0.0625f);  // scale to fit f16
        }
}

// ---------------- K3: FC  out[32][256] = (X/16) * (16*fc_w)^T + fc_b -------
__global__ __launch_bounds__(64) void k3(const _Float16* __restrict__ X,
                                         const float* __restrict__ fc_w,
                                         const float* __restrict__ fc_b,
                                         float* __restrict__ out)
{
    int nb  = blockIdx.x & 15;               // feature tile of 16
    int kcb = blockIdx.x >> 4;               // k chunk of 1024
    int lane = threadIdx.x, l15 = lane & 15, quad = lane >> 4;

    f32x4 acc[2];
    acc[0] = (f32x4){0.f, 0.f, 0.f, 0.f};
    acc[1] = (f32x4){0.f, 0.f, 0.f, 0.f};

    int kbeg = kcb * 1024;
    for (int k0 = kbeg; k0 < kbeg + 1024; k0 += 32) {
        int kk = k0 + quad * 8;
        half8 a0 = *(const half8*)(X + (size_t)l15 * 4096 + kk);
        half8 a1 = *(const half8*)(X + (size_t)(16 + l15) * 4096 + kk);
        const float* wp = fc_w + (size_t)(nb * 16 + l15) * 4096 + kk;
        float4 f0 = *(const float4*)wp;
        float4 f1 = *(const float4*)(wp + 4);
        half8 b0;
        b0[0] = (_Float16)(f0.x * 16.0f);
        b0[1] = (_Float16)(f0.y * 16.0f);
        b0[2] = (_Float16)(f0.z * 16.0f);
        b0[3] = (_Float16)(f0.w * 16.0f);
        b0[4] = (_Float16)(f1.x * 16.0f);
        b0[5] = (_Float16)(f1.y * 16.0f);
        b0[6] = (_Float16)(f1.z * 16.0f);
        b0[7] = (_Float16)(f1.w * 16.0f);
        acc[0] = __builtin_amdgcn_mfma_f32_16x16x32_f16(a0, b0, acc[0], 0, 0, 0);
        acc[1] = __builtin_amdgcn_mfma_f32_16x16x32_f16(a1, b0, acc[1], 0, 0, 0);
    }

    for (int mi = 0; mi < 2; ++mi)
        for (int r = 0; r < 4; ++r) {
            int m = mi * 16 + quad * 4 + r;      // batch row
            int f = nb * 16 + l15;               // feature
            float v = acc[mi][r];
            if (kcb == 0) v += fc_b[f];
            atomicAdd(out + m * 256 + f, v);
        }
}

// ---------------------------------------------------------------------------
extern "C" void kernel_launch(void* const* d_in, const int* in_sizes, int n_in,
                              void* d_out, int out_size, void* d_ws, size_t ws_size,
                              hipStream_t stream) {
    const float* x    = (const float*)d_in[0];
    const float* fc_w = (const float*)d_in[1];
    const float* fc_b = (const float*)d_in[2];
    float* out = (float*)d_out;

    char* ws = (char*)d_ws;
    _Float16* basisA = (_Float16*)(ws + 0);          // 128*512*2    = 131072
    _Float16* P      = (_Float16*)(ws + 131072);     // 32*128*512*2 = 4194304
    _Float16* X      = (_Float16*)(ws + 4325376);    // 32*4096*2    = 262144
                                                     // total ~4.6 MB

    k_prep<<<256, 256, 0, stream>>>(basisA);
    k1<<<dim3(16, 32), 256, 0, stream>>>(x, basisA, P);
    k2<<<dim3(2, 32), 128, 0, stream>>>(basisA, P, X);
    hipMemsetAsync(d_out, 0, (size_t)out_size * sizeof(float), stream);
    k3<<<64, 64, 0, stream>>>(X, fc_w, fc_b, out);
}